// Round 15
// baseline (178.367 us; speedup 1.0000x reference)
//
#include <hip/hip_runtime.h>

typedef short bf16x8 __attribute__((ext_vector_type(8)));
typedef short bf16x4 __attribute__((ext_vector_type(4)));
typedef float f32x4 __attribute__((ext_vector_type(4)));
typedef unsigned short ushort8 __attribute__((ext_vector_type(8)));
typedef unsigned short ushort4v __attribute__((ext_vector_type(4)));
typedef unsigned int uint4v __attribute__((ext_vector_type(4)));
typedef float float4v __attribute__((ext_vector_type(4)));

#define LOG2E 1.4426950408889634f
#define MASKED_VAL -14426.950408889634f /* -10000 * log2(e) */

__device__ __forceinline__ unsigned short f2bf(float f) {
  unsigned u = __builtin_bit_cast(unsigned, f);
  u = u + 0x7fffu + ((u >> 16) & 1u);
  return (unsigned short)(u >> 16);
}

__device__ __forceinline__ unsigned pk2(float a, float b) {
  unsigned r;
  asm("v_cvt_pk_bf16_f32 %0, %1, %2" : "=v"(r) : "v"(a), "v"(b));
  return r;
}

__device__ __forceinline__ float exp2a(float x) {
  float r;
  asm("v_exp_f32 %0, %1" : "=v"(r) : "v"(x));
  return r;
}

__device__ __forceinline__ void gload16(const void* g, void* l) {
  __builtin_amdgcn_global_load_lds(
      (const __attribute__((address_space(1))) unsigned int*)g,
      (__attribute__((address_space(3))) unsigned int*)l, 16, 0, 0);
}

// ---------------- W [K][N] fp32 -> Wt [N][K] bf16, all 4 weights fused ----------------
__global__ __launch_bounds__(256) void transpose_w4(const float* __restrict__ W0,
                                                    const float* __restrict__ W1,
                                                    const float* __restrict__ W2,
                                                    const float* __restrict__ W3,
                                                    unsigned short* __restrict__ Wt) {
  __shared__ float tile[32][33];
  const int z = blockIdx.z;
  const float* W = (z == 0) ? W0 : (z == 1) ? W1 : (z == 2) ? W2 : W3;
  unsigned short* o = Wt + (size_t)z * (1 << 20);
  int bx = blockIdx.x * 32;
  int by = blockIdx.y * 32;
  int tx = threadIdx.x & 31;
  int ty = threadIdx.x >> 5;
#pragma unroll
  for (int j = 0; j < 32; j += 8)
    tile[ty + j][tx] = W[(size_t)(by + ty + j) * 1024 + bx + tx];
  __syncthreads();
#pragma unroll
  for (int j = 0; j < 32; j += 8)
    o[(size_t)(bx + ty + j) * 1024 + by + tx] = f2bf(tile[tx][ty + j]);
}

// ---------------- Fused Q/K/V projection GEMM (128x128, 3-buffer, no-drain barriers) ----------------
__global__ __launch_bounds__(256, 3) void gemm_qkv(
    const float* __restrict__ srcQ, const float* __restrict__ srcK,
    const float* __restrict__ srcV, const unsigned short* __restrict__ Wt,
    const float* __restrict__ bq, const float* __restrict__ bk,
    const float* __restrict__ bv, unsigned short* __restrict__ Qb,
    unsigned short* __restrict__ Kb, unsigned short* __restrict__ Vt) {
  __shared__ __align__(16) unsigned short As[3][128 * 32];  // 24 KB
  __shared__ __align__(16) unsigned short Bs[3][128 * 32];  // 24 KB
  const int K = 1024, N = 1024;
  const int chunk = blockIdx.x >> 9;
  const int inner = blockIdx.x & 511;
  const int x = inner & 7, i = inner >> 3;
  const int bm = (x << 3) + (i >> 3);
  const int bn = i & 7;
  const float* Af = (chunk == 0) ? srcQ : (chunk == 1) ? srcK : srcV;
  const unsigned short* Bt = Wt + (size_t)chunk * (1 << 20);
  const float* bias = (chunk == 0) ? bq : (chunk == 1) ? bk : bv;
  const float scale = (chunk == 0) ? LOG2E : 1.0f;
  const int t = threadIdx.x;
  const int lane = t & 63, wid = t >> 6;
  const int wr = wid >> 1, wc = wid & 1;
  const int lr = lane & 15, lg = lane >> 4;
  f32x4 acc[4][4] = {};
  const size_t baseA = (size_t)(bm * 128) * K;
  const size_t baseB = (size_t)(bn * 128) * K;
  const int c0 = t, c1 = t + 256;
  const size_t a0off = baseA + (size_t)(c0 >> 2) * K + (c0 & 3) * 8;
  const size_t a1off = baseA + (size_t)(c1 >> 2) * K + (c1 & 3) * 8;
  const size_t b0off = baseB + (size_t)(c0 >> 2) * K + (c0 & 3) * 8;
  const size_t b1off = baseB + (size_t)(c1 >> 2) * K + (c1 & 3) * 8;

  unsigned short* pA0 = &As[0][0];
  unsigned short* pA1 = &As[1][0];
  unsigned short* pA2 = &As[2][0];
  unsigned short* pB0 = &Bs[0][0];
  unsigned short* pB1 = &Bs[1][0];
  unsigned short* pB2 = &Bs[2][0];
  float4v fE[4], fO[4];

  auto loadA = [&](float4v* f, int ks) {
    f[0] = *(const float4v*)&Af[a0off + ks];
    f[1] = *(const float4v*)&Af[a0off + ks + 4];
    f[2] = *(const float4v*)&Af[a1off + ks];
    f[3] = *(const float4v*)&Af[a1off + ks + 4];
  };
  auto writeA = [&](const float4v* f, unsigned short* dst) {
    uint4v w0, w1;
    w0[0] = pk2(f[0][0], f[0][1]); w0[1] = pk2(f[0][2], f[0][3]);
    w0[2] = pk2(f[1][0], f[1][1]); w0[3] = pk2(f[1][2], f[1][3]);
    w1[0] = pk2(f[2][0], f[2][1]); w1[1] = pk2(f[2][2], f[2][3]);
    w1[2] = pk2(f[3][0], f[3][1]); w1[3] = pk2(f[3][2], f[3][3]);
    *(uint4v*)&dst[c0 * 8] = w0;
    *(uint4v*)&dst[c1 * 8] = w1;
  };
  auto compute = [&]() {
    bf16x8 a[4], b[4];
#pragma unroll
    for (int m = 0; m < 4; ++m)
      a[m] = *(const bf16x8*)&pA0[(wr * 64 + 16 * m + lr) * 32 + lg * 8];
#pragma unroll
    for (int n = 0; n < 4; ++n)
      b[n] = *(const bf16x8*)&pB0[(wc * 64 + 16 * n + lr) * 32 + lg * 8];
    __builtin_amdgcn_s_setprio(1);
#pragma unroll
    for (int m = 0; m < 4; ++m)
#pragma unroll
      for (int n = 0; n < 4; ++n)
        acc[m][n] = __builtin_amdgcn_mfma_f32_16x16x32_bf16(a[m], b[n], acc[m][n], 0, 0, 0);
    __builtin_amdgcn_s_setprio(0);
  };
  auto rotate = [&]() {
    unsigned short* ta = pA0; pA0 = pA1; pA1 = pA2; pA2 = ta;
    unsigned short* tb = pB0; pB0 = pB1; pB1 = pB2; pB2 = tb;
  };

  gload16(&Bt[b0off], &pB0[c0 * 8]);
  gload16(&Bt[b1off], &pB0[c1 * 8]);
  loadA(fE, 0);
  gload16(&Bt[b0off + 32], &pB1[c0 * 8]);
  gload16(&Bt[b1off + 32], &pB1[c1 * 8]);
  loadA(fO, 32);
  writeA(fE, pA0);
  asm volatile("s_waitcnt lgkmcnt(0)" ::: "memory");
  __builtin_amdgcn_s_barrier();

  for (int it = 0; it < 16; ++it) {
    const int ks0 = 64 * it;
    if (it < 15) {
      gload16(&Bt[b0off + ks0 + 64], &pB2[c0 * 8]);
      gload16(&Bt[b1off + ks0 + 64], &pB2[c1 * 8]);
      loadA(fE, ks0 + 64);
    }
    compute();
    writeA(fO, pA1);
    asm volatile("s_waitcnt lgkmcnt(0)" ::: "memory");
    __builtin_amdgcn_sched_barrier(0);
    __builtin_amdgcn_s_barrier();
    rotate();
    if (it < 15) {
      gload16(&Bt[b0off + ks0 + 96], &pB2[c0 * 8]);
      gload16(&Bt[b1off + ks0 + 96], &pB2[c1 * 8]);
      loadA(fO, ks0 + 96);
    }
    compute();
    if (it < 15) {
      writeA(fE, pA1);
      asm volatile("s_waitcnt lgkmcnt(0)" ::: "memory");
      __builtin_amdgcn_sched_barrier(0);
      __builtin_amdgcn_s_barrier();
      rotate();
    }
  }

  const int rowb = bm * 128 + wr * 64;
  const int colb = bn * 128 + wc * 64;
  if (chunk == 2) {
    const int bidx = rowb >> 11;
    const int srow = rowb & 2047;
#pragma unroll
    for (int n = 0; n < 4; ++n) {
      int col = colb + 16 * n + lr;
      float bv_ = bias[col];
#pragma unroll
      for (int m = 0; m < 4; ++m) {
        int s0 = srow + 16 * m + 4 * lg;
        ushort4v u;
#pragma unroll
        for (int r = 0; r < 4; ++r) u[r] = f2bf(acc[m][n][r] + bv_);
        *(ushort4v*)&Vt[((size_t)(bidx * 1024 + col)) * 2048 + s0] = u;
      }
    }
  } else {
    unsigned short* C = (chunk == 0) ? Qb : Kb;
#pragma unroll
    for (int n = 0; n < 4; ++n) {
      int col = colb + 16 * n + lr;
      float bv_ = bias[col];
#pragma unroll
      for (int m = 0; m < 4; ++m) {
        int row0 = rowb + 16 * m + 4 * lg;
#pragma unroll
        for (int r = 0; r < 4; ++r)
          C[(size_t)(row0 + r) * N + col] = f2bf((acc[m][n][r] + bv_) * scale);
      }
    }
  }
}

// ---------------- Wo GEMM: out = ctx(bf16) * Wt^T + bias (fp32 out) ----------------
__global__ __launch_bounds__(256, 3) void gemm_out(const unsigned short* __restrict__ A,
                                                   const unsigned short* __restrict__ Bt,
                                                   const float* __restrict__ bias,
                                                   float* __restrict__ C) {
  __shared__ __align__(16) unsigned short As[3][128 * 32];
  __shared__ __align__(16) unsigned short Bs[3][128 * 32];
  const int K = 1024, N = 1024;
  const int x = blockIdx.x & 7, i = blockIdx.x >> 3;
  const int bm = (x << 3) + (i >> 3);
  const int bn = i & 7;
  const int t = threadIdx.x;
  const int lane = t & 63, wid = t >> 6;
  const int wr = wid >> 1, wc = wid & 1;
  const int lr = lane & 15, lg = lane >> 4;
  f32x4 acc[4][4] = {};
  const size_t baseA = (size_t)(bm * 128) * K;
  const size_t baseB = (size_t)(bn * 128) * K;
  const int c0 = t, c1 = t + 256;
  const size_t a0off = baseA + (size_t)(c0 >> 2) * K + (c0 & 3) * 8;
  const size_t a1off = baseA + (size_t)(c1 >> 2) * K + (c1 & 3) * 8;
  const size_t b0off = baseB + (size_t)(c0 >> 2) * K + (c0 & 3) * 8;
  const size_t b1off = baseB + (size_t)(c1 >> 2) * K + (c1 & 3) * 8;

  unsigned short* pA0 = &As[0][0];
  unsigned short* pA1 = &As[1][0];
  unsigned short* pA2 = &As[2][0];
  unsigned short* pB0 = &Bs[0][0];
  unsigned short* pB1 = &Bs[1][0];
  unsigned short* pB2 = &Bs[2][0];

  auto issue = [&](int ks, unsigned short* dA, unsigned short* dB) {
    gload16(&A[a0off + ks], &dA[c0 * 8]);
    gload16(&A[a1off + ks], &dA[c1 * 8]);
    gload16(&Bt[b0off + ks], &dB[c0 * 8]);
    gload16(&Bt[b1off + ks], &dB[c1 * 8]);
  };
  auto rotate = [&]() {
    unsigned short* ta = pA0; pA0 = pA1; pA1 = pA2; pA2 = ta;
    unsigned short* tb = pB0; pB0 = pB1; pB1 = pB2; pB2 = tb;
  };

  issue(0, pA0, pB0);
  issue(32, pA1, pB1);
  asm volatile("s_waitcnt vmcnt(4)" ::: "memory");
  __builtin_amdgcn_sched_barrier(0);
  __builtin_amdgcn_s_barrier();

  for (int tt = 0; tt < 32; ++tt) {
    if (tt < 30) issue(32 * tt + 64, pA2, pB2);
    bf16x8 a[4], b[4];
#pragma unroll
    for (int m = 0; m < 4; ++m)
      a[m] = *(const bf16x8*)&pA0[(wr * 64 + 16 * m + lr) * 32 + lg * 8];
#pragma unroll
    for (int n = 0; n < 4; ++n)
      b[n] = *(const bf16x8*)&pB0[(wc * 64 + 16 * n + lr) * 32 + lg * 8];
    __builtin_amdgcn_s_setprio(1);
#pragma unroll
    for (int m = 0; m < 4; ++m)
#pragma unroll
      for (int n = 0; n < 4; ++n)
        acc[m][n] = __builtin_amdgcn_mfma_f32_16x16x32_bf16(a[m], b[n], acc[m][n], 0, 0, 0);
    __builtin_amdgcn_s_setprio(0);
    if (tt < 31) {
      if (tt < 30) {
        asm volatile("s_waitcnt vmcnt(4)" ::: "memory");
      } else {
        asm volatile("s_waitcnt vmcnt(0)" ::: "memory");
      }
      __builtin_amdgcn_sched_barrier(0);
      __builtin_amdgcn_s_barrier();
      rotate();
    }
  }

  const int rowb = bm * 128 + wr * 64;
  const int colb = bn * 128 + wc * 64;
#pragma unroll
  for (int n = 0; n < 4; ++n) {
    int col = colb + 16 * n + lr;
    float bv = bias[col];
#pragma unroll
    for (int m = 0; m < 4; ++m) {
      int row0 = rowb + 16 * m + 4 * lg;
#pragma unroll
      for (int r = 0; r < 4; ++r)
        C[(size_t)(row0 + r) * N + col] = acc[m][n][r] + bv;
    }
  }
}

// ---------------- Flash attention (8 waves, KVBLK=128: 2 sub-tiles per barrier) ----------------
// grid = 512, XCD-swizzled. 8 waves x 32 q-rows. Double-tile staging halves the
// barrier count (16 instead of 32); per-barrier two 64-key sub-bodies whose
// QK/PV streams are independent (wider scheduling window). LDS 64 KB, 2 blk/CU.
__global__ __launch_bounds__(512, 4) void attn_kernel(
    const unsigned short* __restrict__ Q, const unsigned short* __restrict__ K,
    const unsigned short* __restrict__ V, const int* __restrict__ mask,
    unsigned short* __restrict__ ctx) {
  __shared__ __align__(16) unsigned short Kpool[2][8192];  // 32 KB (Q tile staged here pre-loop)
  __shared__ __align__(16) unsigned short Vpool[2][8192];  // 32 KB
  __shared__ int s_any[8];
  const int g = blockIdx.x;
  const int bid = (g & 7) * 64 + (g >> 3);  // XCD-contiguous logical id
  const int qb = bid & 7, h = (bid >> 3) & 15, b = bid >> 7;
  const int t = threadIdx.x;
  const int lane = t & 63, wid = t >> 6;
  const int lr = lane & 15, lg = lane >> 4;
  const size_t rowQ0 = (size_t)(b * 2048 + qb * 256);
  const int hcol = h * 64;
  const size_t vrow0 = (size_t)((b * 16 + h) * 64) * 2048;

  // staging: double-tile = 2 subs x (64 rows x 64 cols) = 1024 chunks; 2/thread
  size_t ksrc[2], vsrc[2];
  int ldso[2];
#pragma unroll
  for (int i = 0; i < 2; ++i) {
    int ci = t + 512 * i;          // 0..1023
    int sub = ci >> 9;             // 0/1
    int cc = ci & 511;
    int row = cc >> 3, pos = cc & 7;
    ksrc[i] = (size_t)(b * 2048 + sub * 64 + row) * 1024 + hcol + ((pos ^ (row & 7)) << 3);
    vsrc[i] = vrow0 + (size_t)row * 2048 + sub * 64 + ((pos ^ ((row >> 1) & 7)) << 3);
    ldso[i] = ci * 8;              // = sub*4096 + row*64 + pos*8
  }
  unsigned short* Kflat = &Kpool[0][0];
  // stage Q tile [256 q][64 d] into Kpool (32 KB exactly)
#pragma unroll
  for (int i = 0; i < 4; ++i) {
    int ci = t + 512 * i;
    int row = ci >> 3, pos = ci & 7;
    gload16(&Q[(rowQ0 + row) * 1024 + hcol + ((pos ^ (row & 7)) << 3)], &Kflat[ci * 8]);
  }
  // block-wide mask scan (4 ints per thread)
  const int* mb = mask + b * 2048;
  int4 mv0 = *(const int4*)&mb[t * 4];
  int bad = (mv0.x == 0) | (mv0.y == 0) | (mv0.z == 0) | (mv0.w == 0);
  unsigned long long bb = __ballot(bad);
  if (lane == 0) s_any[wid] = (bb != 0ULL);
  __syncthreads();  // Q staged + s_any visible
  bf16x8 aq[2][2];
#pragma unroll
  for (int m = 0; m < 2; ++m)
#pragma unroll
    for (int kd = 0; kd < 2; ++kd) {
      int row = wid * 32 + 16 * m + lr;
      int ch = (4 * kd + lg) ^ (lr & 7);
      aq[m][kd] = *(const bf16x8*)&Kflat[row * 64 + ch * 8];
    }
  int anyi = 0;
#pragma unroll
  for (int w = 0; w < 8; ++w) anyi |= s_any[w];
  const bool anymask = anyi != 0;
  __syncthreads();  // Q reads done -> Kpool reusable
#pragma unroll
  for (int i = 0; i < 2; ++i) gload16(&K[ksrc[i]], &Kpool[0][ldso[i]]);
#pragma unroll
  for (int i = 0; i < 2; ++i) gload16(&V[vsrc[i]], &Vpool[0][ldso[i]]);
  __syncthreads();  // double-tile 0 ready

  f32x4 o[2][4] = {};
  f32x4 ol[2] = {};
  const short oneb = 0x3F80;
  const bf16x8 ones8 = {oneb, oneb, oneb, oneb, oneb, oneb, oneb, oneb};
  const f32x4 zero4 = {0.f, 0.f, 0.f, 0.f};
  const int ch0 = (lg ^ (lr & 7)) * 8;
  const int ch1 = ((4 + lg) ^ (lr & 7)) * 8;
  const int sw = lr >> 1;

  for (int kt = 0; kt < 16; ++kt) {
    const int bi = kt & 1;
    const unsigned short* Kb_ = &Kpool[bi][0];
    const unsigned short* Vb_ = &Vpool[bi][0];
    unsigned short* Kn_ = &Kpool[bi ^ 1][0];
    unsigned short* Vn_ = &Vpool[bi ^ 1][0];
    if (kt + 1 < 16) {
      const size_t ko = (size_t)(kt + 1) * 128 * 1024;
      const size_t vo = (size_t)(kt + 1) * 128;
#pragma unroll
      for (int i = 0; i < 2; ++i) gload16(&K[ksrc[i] + ko], &Kn_[ldso[i]]);
#pragma unroll
      for (int i = 0; i < 2; ++i) gload16(&V[vsrc[i] + vo], &Vn_[ldso[i]]);
    }
#pragma unroll
    for (int sub = 0; sub < 2; ++sub) {
      const unsigned short* Ks_ = Kb_ + sub * 4096;
      const unsigned short* Vs_ = Vb_ + sub * 4096;
      // ---- S^T = K Q^T ----
      f32x4 s[2][4];
      __builtin_amdgcn_s_setprio(1);
#pragma unroll
      for (int n = 0; n < 4; ++n) {
        bf16x8 k0 = *(const bf16x8*)&Ks_[(16 * n + lr) * 64 + ch0];
        bf16x8 k1 = *(const bf16x8*)&Ks_[(16 * n + lr) * 64 + ch1];
        f32x4 t0 = __builtin_amdgcn_mfma_f32_16x16x32_bf16(k0, aq[0][0], zero4, 0, 0, 0);
        s[0][n] = __builtin_amdgcn_mfma_f32_16x16x32_bf16(k1, aq[0][1], t0, 0, 0, 0);
        f32x4 t1 = __builtin_amdgcn_mfma_f32_16x16x32_bf16(k0, aq[1][0], zero4, 0, 0, 0);
        s[1][n] = __builtin_amdgcn_mfma_f32_16x16x32_bf16(k1, aq[1][1], t1, 0, 0, 0);
      }
      __builtin_amdgcn_s_setprio(0);
      if (anymask) {
        const int* mrow = mb + kt * 128 + sub * 64;
#pragma unroll
        for (int n = 0; n < 4; ++n) {
          int4 mv = *(const int4*)&mrow[16 * n + 4 * lg];
          int mm[4] = {mv.x, mv.y, mv.z, mv.w};
#pragma unroll
          for (int r = 0; r < 4; ++r)
            if (mm[r] == 0) { s[0][n][r] = MASKED_VAL; s[1][n][r] = MASKED_VAL; }
        }
      }
      // ---- direct exp2 (bounded scores) ----
#pragma unroll
      for (int m = 0; m < 2; ++m)
#pragma unroll
        for (int n = 0; n < 4; ++n)
#pragma unroll
          for (int r = 0; r < 4; ++r) s[m][n][r] = exp2a(s[m][n][r]);
      // ---- O^T += V^T P^T (permuted k-slots); l via ones-MFMA ----
#pragma unroll
      for (int kk = 0; kk < 2; ++kk) {
        bf16x8 pf[2];
#pragma unroll
        for (int m = 0; m < 2; ++m) {
          uint4v u;
          u[0] = pk2(s[m][2 * kk][0], s[m][2 * kk][1]);
          u[1] = pk2(s[m][2 * kk][2], s[m][2 * kk][3]);
          u[2] = pk2(s[m][2 * kk + 1][0], s[m][2 * kk + 1][1]);
          u[3] = pk2(s[m][2 * kk + 1][2], s[m][2 * kk + 1][3]);
          pf[m] = __builtin_bit_cast(bf16x8, u);
        }
        __builtin_amdgcn_s_setprio(1);
        ol[0] = __builtin_amdgcn_mfma_f32_16x16x32_bf16(ones8, pf[0], ol[0], 0, 0, 0);
        ol[1] = __builtin_amdgcn_mfma_f32_16x16x32_bf16(ones8, pf[1], ol[1], 0, 0, 0);
        const int p0 = (4 * kk + (lg >> 1)) ^ sw;
        const int base0 = lr * 64 + p0 * 8 + (lg & 1) * 4;
        const int base1 = lr * 64 + (p0 ^ 2) * 8 + (lg & 1) * 4;
#pragma unroll
        for (int dn = 0; dn < 4; ++dn) {
          bf16x4 v0 = *(const bf16x4*)&Vs_[base0 + dn * 1024];
          bf16x4 v1 = *(const bf16x4*)&Vs_[base1 + dn * 1024];
          bf16x8 vb = __builtin_shufflevector(v0, v1, 0, 1, 2, 3, 4, 5, 6, 7);
#pragma unroll
          for (int m = 0; m < 2; ++m)
            o[m][dn] = __builtin_amdgcn_mfma_f32_16x16x32_bf16(vb, pf[m], o[m][dn], 0, 0, 0);
        }
        __builtin_amdgcn_s_setprio(0);
      }
    }
    __syncthreads();  // drains next double-tile stage; all reads of buf bi done
  }
  // ---- epilogue ----
#pragma unroll
  for (int m = 0; m < 2; ++m) {
    float inv = 1.f / ol[m][0];
    size_t q = rowQ0 + wid * 32 + 16 * m + lr;
#pragma unroll
    for (int dn = 0; dn < 4; ++dn) {
      ushort4v u;
#pragma unroll
      for (int r = 0; r < 4; ++r) u[r] = f2bf(o[m][dn][r] * inv);
      *(ushort4v*)&ctx[q * 1024 + hcol + 16 * dn + 4 * lg] = u;
    }
  }
}

extern "C" void kernel_launch(void* const* d_in, const int* in_sizes, int n_in,
                              void* d_out, int out_size, void* d_ws, size_t ws_size,
                              hipStream_t stream) {
  const float* srcQ = (const float*)d_in[0];
  const float* srcK = (const float*)d_in[1];
  const float* srcV = (const float*)d_in[2];
  const int*   mask = (const int*)d_in[3];
  const float* Wq = (const float*)d_in[4];
  const float* bq = (const float*)d_in[5];
  const float* Wk = (const float*)d_in[6];
  const float* bk = (const float*)d_in[7];
  const float* Wv = (const float*)d_in[8];
  const float* bv = (const float*)d_in[9];
  const float* Wo = (const float*)d_in[10];
  const float* bo = (const float*)d_in[11];
  float* out = (float*)d_out;

  char* ws = (char*)d_ws;
  unsigned short* ctx = (unsigned short*)(ws);                       // 16 MiB
  unsigned short* Qb  = (unsigned short*)(ws + (size_t)(16 << 20));
  unsigned short* Kb  = (unsigned short*)(ws + (size_t)(32 << 20));
  unsigned short* Vt  = (unsigned short*)(ws + (size_t)(48 << 20));  // V^T from V-GEMM
  unsigned short* Wt  = (unsigned short*)(ws + (size_t)(64 << 20));  // 4 x 2 MiB

  transpose_w4<<<dim3(32, 32, 4), 256, 0, stream>>>(Wq, Wk, Wv, Wo, Wt);

  gemm_qkv<<<1536, 256, 0, stream>>>(srcQ, srcK, srcV, Wt, bq, bk, bv, Qb, Kb, Vt);

  attn_kernel<<<512, 512, 0, stream>>>(Qb, Kb, Vt, mask, ctx);

  gemm_out<<<512, 256, 0, stream>>>(ctx, Wt + 3 * (1 << 20), bo, out);
}

// Round 16
// 169.216 us; speedup vs baseline: 1.0541x; 1.0541x over previous
//
#include <hip/hip_runtime.h>

typedef short bf16x8 __attribute__((ext_vector_type(8)));
typedef short bf16x4 __attribute__((ext_vector_type(4)));
typedef float f32x4 __attribute__((ext_vector_type(4)));
typedef unsigned short ushort8 __attribute__((ext_vector_type(8)));
typedef unsigned short ushort4v __attribute__((ext_vector_type(4)));
typedef unsigned int uint4v __attribute__((ext_vector_type(4)));
typedef float float4v __attribute__((ext_vector_type(4)));

#define LOG2E 1.4426950408889634f
#define MASKED_VAL -14426.950408889634f /* -10000 * log2(e) */

__device__ __forceinline__ unsigned short f2bf(float f) {
  unsigned u = __builtin_bit_cast(unsigned, f);
  u = u + 0x7fffu + ((u >> 16) & 1u);
  return (unsigned short)(u >> 16);
}

__device__ __forceinline__ unsigned pk2(float a, float b) {
  unsigned r;
  asm("v_cvt_pk_bf16_f32 %0, %1, %2" : "=v"(r) : "v"(a), "v"(b));
  return r;
}

__device__ __forceinline__ float exp2a(float x) {
  float r;
  asm("v_exp_f32 %0, %1" : "=v"(r) : "v"(x));
  return r;
}

__device__ __forceinline__ void gload16(const void* g, void* l) {
  __builtin_amdgcn_global_load_lds(
      (const __attribute__((address_space(1))) unsigned int*)g,
      (__attribute__((address_space(3))) unsigned int*)l, 16, 0, 0);
}

// ---------------- W [K][N] fp32 -> fragment-packed bf16 ----------------
// Packed layout (elements): off = (bn*32+ks)*4096 + (wc*4+n)*512 + (lg*16+lr)*8 + j
// where col = bn*128 + wc*64 + 16n + lr, k = 32*ks + 8*lg + j. A wave's B-frag
// load is then one coalesced 16B/lane read at slab + (wc*4+n)*512 + lane*8.
__global__ __launch_bounds__(256) void pack_w4(const float* __restrict__ W0,
                                               const float* __restrict__ W1,
                                               const float* __restrict__ W2,
                                               const float* __restrict__ W3,
                                               unsigned short* __restrict__ P) {
  __shared__ float tile[32][33];
  const int z = blockIdx.z;
  const float* W = (z == 0) ? W0 : (z == 1) ? W1 : (z == 2) ? W2 : W3;
  unsigned short* o = P + (size_t)z * (1 << 20);
  int bx = blockIdx.x * 32;  // col base
  int by = blockIdx.y * 32;  // k base
  int tx = threadIdx.x & 31;
  int ty = threadIdx.x >> 5;
#pragma unroll
  for (int j = 0; j < 32; j += 8)
    tile[ty + j][tx] = W[(size_t)(by + ty + j) * 1024 + bx + tx];  // tile[k][col]
  __syncthreads();
  const int t = threadIdx.x;
  if (t < 128) {
    int col_l = t & 31, kg = t >> 5;  // kg = lg (by is a multiple of 32)
    int col = bx + col_l;
    ushort8 v;
#pragma unroll
    for (int j = 0; j < 8; ++j) v[j] = f2bf(tile[kg * 8 + j][col_l]);
    int bn = col >> 7, cl = col & 127;
    int wc = cl >> 6, n = (cl >> 4) & 3, lr = cl & 15;
    int ks = by >> 5;
    size_t off = (size_t)(bn * 32 + ks) * 4096 + (wc * 4 + n) * 512 + (kg * 16 + lr) * 8;
    *(ushort8*)&o[off] = v;
  }
}

// ---------------- Fused Q/K/V projection GEMM ----------------
// 128x128, A: fp32 reg-staged -> cvt -> LDS (3-buffer, no-drain lgkm barriers).
// B: fragment-packed weights, DIRECT to registers (no LDS at all for B).
__global__ __launch_bounds__(256, 3) void gemm_qkv(
    const float* __restrict__ srcQ, const float* __restrict__ srcK,
    const float* __restrict__ srcV, const unsigned short* __restrict__ Wp,
    const float* __restrict__ bq, const float* __restrict__ bk,
    const float* __restrict__ bv, unsigned short* __restrict__ Qb,
    unsigned short* __restrict__ Kb, unsigned short* __restrict__ Vt) {
  __shared__ __align__(16) unsigned short As[3][128 * 32];  // 24 KB total
  const int K = 1024, N = 1024;
  const int chunk = blockIdx.x >> 9;
  const int inner = blockIdx.x & 511;
  const int x = inner & 7, i = inner >> 3;
  const int bm = (x << 3) + (i >> 3);
  const int bn = i & 7;
  const float* Af = (chunk == 0) ? srcQ : (chunk == 1) ? srcK : srcV;
  const unsigned short* Pk = Wp + (size_t)chunk * (1 << 20);
  const float* bias = (chunk == 0) ? bq : (chunk == 1) ? bk : bv;
  const float scale = (chunk == 0) ? LOG2E : 1.0f;
  const int t = threadIdx.x;
  const int lane = t & 63, wid = t >> 6;
  const int wr = wid >> 1, wc = wid & 1;
  const int lr = lane & 15, lg = lane >> 4;
  f32x4 acc[4][4] = {};
  const size_t baseA = (size_t)(bm * 128) * K;
  const int c0 = t, c1 = t + 256;
  const size_t a0off = baseA + (size_t)(c0 >> 2) * K + (c0 & 3) * 8;
  const size_t a1off = baseA + (size_t)(c1 >> 2) * K + (c1 & 3) * 8;
  // packed B fragment offsets (elements); slab stride = 4096 elems per ks
  size_t bo[4];
#pragma unroll
  for (int n = 0; n < 4; ++n)
    bo[n] = (size_t)(bn * 32) * 4096 + (size_t)(wc * 4 + n) * 512 + (size_t)lane * 8;

  unsigned short* pA0 = &As[0][0];
  unsigned short* pA1 = &As[1][0];
  unsigned short* pA2 = &As[2][0];
  float4v fE[4], fO[4];
  bf16x8 bE[4], bO[4];

  auto loadA = [&](float4v* f, int ke) {  // ke = element offset in K
    f[0] = *(const float4v*)&Af[a0off + ke];
    f[1] = *(const float4v*)&Af[a0off + ke + 4];
    f[2] = *(const float4v*)&Af[a1off + ke];
    f[3] = *(const float4v*)&Af[a1off + ke + 4];
  };
  auto loadB = [&](bf16x8* b, int ks) {
#pragma unroll
    for (int n = 0; n < 4; ++n)
      b[n] = *(const bf16x8*)&Pk[bo[n] + (size_t)ks * 4096];
  };
  auto writeA = [&](const float4v* f, unsigned short* dst) {
    uint4v w0, w1;
    w0[0] = pk2(f[0][0], f[0][1]); w0[1] = pk2(f[0][2], f[0][3]);
    w0[2] = pk2(f[1][0], f[1][1]); w0[3] = pk2(f[1][2], f[1][3]);
    w1[0] = pk2(f[2][0], f[2][1]); w1[1] = pk2(f[2][2], f[2][3]);
    w1[2] = pk2(f[3][0], f[3][1]); w1[3] = pk2(f[3][2], f[3][3]);
    *(uint4v*)&dst[c0 * 8] = w0;
    *(uint4v*)&dst[c1 * 8] = w1;
  };
  auto compute = [&](const bf16x8* b) {
    bf16x8 a[4];
#pragma unroll
    for (int m = 0; m < 4; ++m)
      a[m] = *(const bf16x8*)&pA0[(wr * 64 + 16 * m + lr) * 32 + lg * 8];
    __builtin_amdgcn_s_setprio(1);
#pragma unroll
    for (int m = 0; m < 4; ++m)
#pragma unroll
      for (int n = 0; n < 4; ++n)
        acc[m][n] = __builtin_amdgcn_mfma_f32_16x16x32_bf16(a[m], b[n], acc[m][n], 0, 0, 0);
    __builtin_amdgcn_s_setprio(0);
  };
  auto rotate = [&]() {
    unsigned short* ta = pA0; pA0 = pA1; pA1 = pA2; pA2 = ta;
  };

  // prologue: A(0),A(1) in regs; B(0),B(1) in regs; publish A(0)
  loadA(fE, 0);
  loadB(bE, 0);
  loadA(fO, 32);
  loadB(bO, 1);
  writeA(fE, pA0);
  asm volatile("s_waitcnt lgkmcnt(0)" ::: "memory");
  __builtin_amdgcn_s_barrier();

  for (int it = 0; it < 16; ++it) {
    const int t0 = 2 * it;
    // ---- even tile t0: uses pA0 + bE ----
    if (it < 15) loadA(fE, 32 * (t0 + 2));
    compute(bE);
    if (t0 + 2 < 32) loadB(bE, t0 + 2);  // reload after last use
    writeA(fO, pA1);
    asm volatile("s_waitcnt lgkmcnt(0)" ::: "memory");
    __builtin_amdgcn_sched_barrier(0);
    __builtin_amdgcn_s_barrier();
    rotate();
    // ---- odd tile t1 = t0+1: uses pA0 + bO ----
    if (it < 15) loadA(fO, 32 * (t0 + 3));
    compute(bO);
    if (t0 + 3 < 32) loadB(bO, t0 + 3);
    if (it < 15) {
      writeA(fE, pA1);
      asm volatile("s_waitcnt lgkmcnt(0)" ::: "memory");
      __builtin_amdgcn_sched_barrier(0);
      __builtin_amdgcn_s_barrier();
      rotate();
    }
  }

  const int rowb = bm * 128 + wr * 64;
  const int colb = bn * 128 + wc * 64;
  if (chunk == 2) {
    const int bidx = rowb >> 11;
    const int srow = rowb & 2047;
#pragma unroll
    for (int n = 0; n < 4; ++n) {
      int col = colb + 16 * n + lr;
      float bv_ = bias[col];
#pragma unroll
      for (int m = 0; m < 4; ++m) {
        int s0 = srow + 16 * m + 4 * lg;
        ushort4v u;
#pragma unroll
        for (int r = 0; r < 4; ++r) u[r] = f2bf(acc[m][n][r] + bv_);
        *(ushort4v*)&Vt[((size_t)(bidx * 1024 + col)) * 2048 + s0] = u;
      }
    }
  } else {
    unsigned short* C = (chunk == 0) ? Qb : Kb;
#pragma unroll
    for (int n = 0; n < 4; ++n) {
      int col = colb + 16 * n + lr;
      float bv_ = bias[col];
#pragma unroll
      for (int m = 0; m < 4; ++m) {
        int row0 = rowb + 16 * m + 4 * lg;
#pragma unroll
        for (int r = 0; r < 4; ++r)
          C[(size_t)(row0 + r) * N + col] = f2bf((acc[m][n][r] + bv_) * scale);
      }
    }
  }
}

// ---------------- Wo GEMM: out = ctx(bf16) * Wo^T + bias (fp32 out) ----------------
// A: ctx via gload_lds 3-buffer (counted vmcnt, never drain mid-loop).
// B: fragment-packed Wo, direct to registers.
__global__ __launch_bounds__(256, 3) void gemm_out(const unsigned short* __restrict__ A,
                                                   const unsigned short* __restrict__ Bp,
                                                   const float* __restrict__ bias,
                                                   float* __restrict__ C) {
  __shared__ __align__(16) unsigned short As[3][128 * 32];
  const int K = 1024, N = 1024;
  const int x = blockIdx.x & 7, i = blockIdx.x >> 3;
  const int bm = (x << 3) + (i >> 3);
  const int bn = i & 7;
  const int t = threadIdx.x;
  const int lane = t & 63, wid = t >> 6;
  const int wr = wid >> 1, wc = wid & 1;
  const int lr = lane & 15, lg = lane >> 4;
  f32x4 acc[4][4] = {};
  const size_t baseA = (size_t)(bm * 128) * K;
  const int c0 = t, c1 = t + 256;
  const size_t a0off = baseA + (size_t)(c0 >> 2) * K + (c0 & 3) * 8;
  const size_t a1off = baseA + (size_t)(c1 >> 2) * K + (c1 & 3) * 8;
  size_t bo[4];
#pragma unroll
  for (int n = 0; n < 4; ++n)
    bo[n] = (size_t)(bn * 32) * 4096 + (size_t)(wc * 4 + n) * 512 + (size_t)lane * 8;

  unsigned short* pA0 = &As[0][0];
  unsigned short* pA1 = &As[1][0];
  unsigned short* pA2 = &As[2][0];
  bf16x8 bE[4], bO[4];

  auto dmaA = [&](int ks, unsigned short* dA) {
    gload16(&A[a0off + 32 * ks], &dA[c0 * 8]);
    gload16(&A[a1off + 32 * ks], &dA[c1 * 8]);
  };
  auto loadB = [&](bf16x8* b, int ks) {
#pragma unroll
    for (int n = 0; n < 4; ++n)
      b[n] = *(const bf16x8*)&Bp[bo[n] + (size_t)ks * 4096];
  };
  auto compute = [&](const bf16x8* b) {
    bf16x8 a[4];
#pragma unroll
    for (int m = 0; m < 4; ++m)
      a[m] = *(const bf16x8*)&pA0[(wr * 64 + 16 * m + lr) * 32 + lg * 8];
    __builtin_amdgcn_s_setprio(1);
#pragma unroll
    for (int m = 0; m < 4; ++m)
#pragma unroll
      for (int n = 0; n < 4; ++n)
        acc[m][n] = __builtin_amdgcn_mfma_f32_16x16x32_bf16(a[m], b[n], acc[m][n], 0, 0, 0);
    __builtin_amdgcn_s_setprio(0);
  };
  auto rotate = [&]() {
    unsigned short* ta = pA0; pA0 = pA1; pA1 = pA2; pA2 = ta;
  };

  // prologue: DMA A(0),A(1); B(0),B(1) to regs. Wait A(0): newer = A(1)2+B loads.
  dmaA(0, pA0);
  dmaA(1, pA1);
  loadB(bE, 0);
  loadB(bO, 1);
  asm volatile("s_waitcnt vmcnt(10)" ::: "memory");
  __builtin_amdgcn_sched_barrier(0);
  __builtin_amdgcn_s_barrier();

  for (int it = 0; it < 16; ++it) {
    const int t0 = 2 * it;
    // ---- even tile t0 ----
    if (t0 + 2 < 32) dmaA(t0 + 2, pA2);
    compute(bE);
    if (t0 + 2 < 32) loadB(bE, t0 + 2);
    {
      // boundary: retire A(t0+1); newer = A(t0+2)[<=2] + B(t0+2)[<=4]
      if (t0 < 30) {
        asm volatile("s_waitcnt vmcnt(6)" ::: "memory");
      } else {
        asm volatile("s_waitcnt vmcnt(0)" ::: "memory");
      }
      __builtin_amdgcn_sched_barrier(0);
      __builtin_amdgcn_s_barrier();
      rotate();
    }
    // ---- odd tile t1 = t0+1 ----
    if (t0 + 3 < 32) dmaA(t0 + 3, pA2);
    compute(bO);
    if (t0 + 3 < 32) loadB(bO, t0 + 3);
    if (it < 15) {
      if (t0 + 1 < 30) {
        asm volatile("s_waitcnt vmcnt(6)" ::: "memory");
      } else {
        asm volatile("s_waitcnt vmcnt(0)" ::: "memory");
      }
      __builtin_amdgcn_sched_barrier(0);
      __builtin_amdgcn_s_barrier();
      rotate();
    }
  }

  const int rowb = bm * 128 + wr * 64;
  const int colb = bn * 128 + wc * 64;
#pragma unroll
  for (int n = 0; n < 4; ++n) {
    int col = colb + 16 * n + lr;
    float bv = bias[col];
#pragma unroll
    for (int m = 0; m < 4; ++m) {
      int row0 = rowb + 16 * m + 4 * lg;
#pragma unroll
      for (int r = 0; r < 4; ++r)
        C[(size_t)(row0 + r) * N + col] = acc[m][n][r] + bv;
    }
  }
}

// ---------------- Flash attention (8 waves/block, 256 q-rows) ----------------
// grid = 512, XCD-swizzled. 8 waves x 32 q-rows, KVBLK=64, dbuf.
__global__ __launch_bounds__(512, 4) void attn_kernel(
    const unsigned short* __restrict__ Q, const unsigned short* __restrict__ K,
    const unsigned short* __restrict__ V, const int* __restrict__ mask,
    unsigned short* __restrict__ ctx) {
  __shared__ __align__(16) unsigned short pool[16384];  // 32 KB
  __shared__ int s_any[8];
  unsigned short* Kbuf0 = pool;
  unsigned short* Kbuf1 = pool + 4096;
  unsigned short* Vbuf0 = pool + 8192;
  unsigned short* Vbuf1 = pool + 12288;
  const int g = blockIdx.x;
  const int bid = (g & 7) * 64 + (g >> 3);  // XCD-contiguous logical id
  const int qb = bid & 7, h = (bid >> 3) & 15, b = bid >> 7;
  const int t = threadIdx.x;
  const int lane = t & 63, wid = t >> 6;
  const int lr = lane & 15, lg = lane >> 4;
  const size_t rowQ0 = (size_t)(b * 2048 + qb * 256);
  const int hcol = h * 64;
  const size_t vrow0 = (size_t)((b * 16 + h) * 64) * 2048;

  const int row_s = t >> 3, pos_s = t & 7;
  const size_t ksrc = (size_t)(b * 2048 + row_s) * 1024 + hcol + ((pos_s ^ (row_s & 7)) << 3);
  const size_t vsrc = vrow0 + (size_t)row_s * 2048 + ((pos_s ^ ((row_s >> 1) & 7)) << 3);
  const int ldso = t * 8;

#pragma unroll
  for (int i = 0; i < 4; ++i) {
    int ci = t + 512 * i;
    int row = ci >> 3, pos = ci & 7;
    gload16(&Q[(rowQ0 + row) * 1024 + hcol + ((pos ^ (row & 7)) << 3)], &pool[ci * 8]);
  }
  const int* mb = mask + b * 2048;
  int4 mv0 = *(const int4*)&mb[t * 4];
  int bad = (mv0.x == 0) | (mv0.y == 0) | (mv0.z == 0) | (mv0.w == 0);
  unsigned long long bb = __ballot(bad);
  if (lane == 0) s_any[wid] = (bb != 0ULL);
  __syncthreads();
  bf16x8 aq[2][2];
#pragma unroll
  for (int m = 0; m < 2; ++m)
#pragma unroll
    for (int kd = 0; kd < 2; ++kd) {
      int row = wid * 32 + 16 * m + lr;
      int ch = (4 * kd + lg) ^ (lr & 7);
      aq[m][kd] = *(const bf16x8*)&pool[row * 64 + ch * 8];
    }
  int anyi = 0;
#pragma unroll
  for (int w = 0; w < 8; ++w) anyi |= s_any[w];
  const bool anymask = anyi != 0;
  __syncthreads();
  gload16(&K[ksrc], &Kbuf0[ldso]);
  gload16(&V[vsrc], &Vbuf0[ldso]);
  __syncthreads();

  f32x4 o[2][4] = {};
  f32x4 ol[2] = {};
  const short oneb = 0x3F80;
  const bf16x8 ones8 = {oneb, oneb, oneb, oneb, oneb, oneb, oneb, oneb};
  const f32x4 zero4 = {0.f, 0.f, 0.f, 0.f};
  const int ch0 = (lg ^ (lr & 7)) * 8;
  const int ch1 = ((4 + lg) ^ (lr & 7)) * 8;
  const int sw = lr >> 1;

  for (int kb = 0; kb < 32; ++kb) {
    const int bi = kb & 1;
    const unsigned short* Kb_ = bi ? Kbuf1 : Kbuf0;
    const unsigned short* Vb_ = bi ? Vbuf1 : Vbuf0;
    unsigned short* Kn_ = bi ? Kbuf0 : Kbuf1;
    unsigned short* Vn_ = bi ? Vbuf0 : Vbuf1;
    if (kb + 1 < 32) {
      gload16(&K[ksrc + (size_t)(kb + 1) * 64 * 1024], &Kn_[ldso]);
      gload16(&V[vsrc + (size_t)(kb + 1) * 64], &Vn_[ldso]);
    }
    f32x4 s[2][4];
    __builtin_amdgcn_s_setprio(1);
#pragma unroll
    for (int n = 0; n < 4; ++n) {
      bf16x8 k0 = *(const bf16x8*)&Kb_[(16 * n + lr) * 64 + ch0];
      bf16x8 k1 = *(const bf16x8*)&Kb_[(16 * n + lr) * 64 + ch1];
      f32x4 t0 = __builtin_amdgcn_mfma_f32_16x16x32_bf16(k0, aq[0][0], zero4, 0, 0, 0);
      s[0][n] = __builtin_amdgcn_mfma_f32_16x16x32_bf16(k1, aq[0][1], t0, 0, 0, 0);
      f32x4 t1 = __builtin_amdgcn_mfma_f32_16x16x32_bf16(k0, aq[1][0], zero4, 0, 0, 0);
      s[1][n] = __builtin_amdgcn_mfma_f32_16x16x32_bf16(k1, aq[1][1], t1, 0, 0, 0);
    }
    __builtin_amdgcn_s_setprio(0);
    if (anymask) {
      const int* mrow = mb + kb * 64;
#pragma unroll
      for (int n = 0; n < 4; ++n) {
        int4 mv = *(const int4*)&mrow[16 * n + 4 * lg];
        int mm[4] = {mv.x, mv.y, mv.z, mv.w};
#pragma unroll
        for (int r = 0; r < 4; ++r)
          if (mm[r] == 0) { s[0][n][r] = MASKED_VAL; s[1][n][r] = MASKED_VAL; }
      }
    }
#pragma unroll
    for (int m = 0; m < 2; ++m)
#pragma unroll
      for (int n = 0; n < 4; ++n)
#pragma unroll
        for (int r = 0; r < 4; ++r) s[m][n][r] = exp2a(s[m][n][r]);
#pragma unroll
    for (int kk = 0; kk < 2; ++kk) {
      bf16x8 pf[2];
#pragma unroll
      for (int m = 0; m < 2; ++m) {
        uint4v u;
        u[0] = pk2(s[m][2 * kk][0], s[m][2 * kk][1]);
        u[1] = pk2(s[m][2 * kk][2], s[m][2 * kk][3]);
        u[2] = pk2(s[m][2 * kk + 1][0], s[m][2 * kk + 1][1]);
        u[3] = pk2(s[m][2 * kk + 1][2], s[m][2 * kk + 1][3]);
        pf[m] = __builtin_bit_cast(bf16x8, u);
      }
      __builtin_amdgcn_s_setprio(1);
      ol[0] = __builtin_amdgcn_mfma_f32_16x16x32_bf16(ones8, pf[0], ol[0], 0, 0, 0);
      ol[1] = __builtin_amdgcn_mfma_f32_16x16x32_bf16(ones8, pf[1], ol[1], 0, 0, 0);
      const int p0 = (4 * kk + (lg >> 1)) ^ sw;
      const int base0 = lr * 64 + p0 * 8 + (lg & 1) * 4;
      const int base1 = lr * 64 + (p0 ^ 2) * 8 + (lg & 1) * 4;
#pragma unroll
      for (int dn = 0; dn < 4; ++dn) {
        bf16x4 v0 = *(const bf16x4*)&Vb_[base0 + dn * 1024];
        bf16x4 v1 = *(const bf16x4*)&Vb_[base1 + dn * 1024];
        bf16x8 vb = __builtin_shufflevector(v0, v1, 0, 1, 2, 3, 4, 5, 6, 7);
#pragma unroll
        for (int m = 0; m < 2; ++m)
          o[m][dn] = __builtin_amdgcn_mfma_f32_16x16x32_bf16(vb, pf[m], o[m][dn], 0, 0, 0);
      }
      __builtin_amdgcn_s_setprio(0);
    }
    __syncthreads();
  }
#pragma unroll
  for (int m = 0; m < 2; ++m) {
    float inv = 1.f / ol[m][0];
    size_t q = rowQ0 + wid * 32 + 16 * m + lr;
#pragma unroll
    for (int dn = 0; dn < 4; ++dn) {
      ushort4v u;
#pragma unroll
      for (int r = 0; r < 4; ++r) u[r] = f2bf(o[m][dn][r] * inv);
      *(ushort4v*)&ctx[q * 1024 + hcol + 16 * dn + 4 * lg] = u;
    }
  }
}

extern "C" void kernel_launch(void* const* d_in, const int* in_sizes, int n_in,
                              void* d_out, int out_size, void* d_ws, size_t ws_size,
                              hipStream_t stream) {
  const float* srcQ = (const float*)d_in[0];
  const float* srcK = (const float*)d_in[1];
  const float* srcV = (const float*)d_in[2];
  const int*   mask = (const int*)d_in[3];
  const float* Wq = (const float*)d_in[4];
  const float* bq = (const float*)d_in[5];
  const float* Wk = (const float*)d_in[6];
  const float* bk = (const float*)d_in[7];
  const float* Wv = (const float*)d_in[8];
  const float* bv = (const float*)d_in[9];
  const float* Wo = (const float*)d_in[10];
  const float* bo = (const float*)d_in[11];
  float* out = (float*)d_out;

  char* ws = (char*)d_ws;
  unsigned short* ctx = (unsigned short*)(ws);                       // 16 MiB
  unsigned short* Qb  = (unsigned short*)(ws + (size_t)(16 << 20));
  unsigned short* Kb  = (unsigned short*)(ws + (size_t)(32 << 20));
  unsigned short* Vt  = (unsigned short*)(ws + (size_t)(48 << 20));  // V^T from V-GEMM
  unsigned short* Wp  = (unsigned short*)(ws + (size_t)(64 << 20));  // 4 x 2 MiB packed

  pack_w4<<<dim3(32, 32, 4), 256, 0, stream>>>(Wq, Wk, Wv, Wo, Wp);

  gemm_qkv<<<1536, 256, 0, stream>>>(srcQ, srcK, srcV, Wp, bq, bk, bv, Qb, Kb, Vt);

  attn_kernel<<<512, 512, 0, stream>>>(Qb, Kb, Vt, mask, ctx);

  gemm_out<<<512, 256, 0, stream>>>(ctx, Wp + 3 * (1 << 20), bo, out);
}